// Round 8
// baseline (19394.191 us; speedup 1.0000x reference)
//
#include <hip/hip_runtime.h>
#include <cmath>

#define L_ 512
#define B_ 128
#define D_ 1024
#define H_ 1024

typedef __attribute__((ext_vector_type(8))) short bf16x8;
typedef __attribute__((ext_vector_type(4))) float f32x4;

static __device__ __forceinline__ unsigned short f32_bf16_rn(float f) {
  unsigned u = __float_as_uint(f);
  u += 0x7FFFu + ((u >> 16) & 1u);
  return (unsigned short)(u >> 16);
}
static __device__ __forceinline__ float bf16_f32(unsigned short h) {
  return __uint_as_float(((unsigned)h) << 16);
}

static __device__ __forceinline__ void pack8(const float4& u, const float4& v,
                                             bf16x8& hi, bf16x8& lo) {
  float f[8] = {u.x, u.y, u.z, u.w, v.x, v.y, v.z, v.w};
#pragma unroll
  for (int i = 0; i < 8; ++i) {
    const unsigned short h = f32_bf16_rn(f[i]);
    hi[i] = (short)h;
    lo[i] = (short)f32_bf16_rn(f[i] - bf16_f32(h));
  }
}

// ---------------------------------------------------------------------------
// Kernel A: xi = x @ Wi^T + bi, split-bf16 3-MFMA. (unchanged — R7-proven)
// ---------------------------------------------------------------------------
__global__ __launch_bounds__(256) void xi_gemm_mfma(
    const float* __restrict__ x, const float* __restrict__ Wi,
    const float* __restrict__ bi, float* __restrict__ out) {
  __shared__ unsigned short Ahi[128 * 32], Alo[128 * 32];
  __shared__ unsigned short Bhi[128 * 32], Blo[128 * 32];
  const int tid = threadIdx.x;
  const int bm = blockIdx.x, bn = blockIdx.y;
  const int lane = tid & 63, wv = tid >> 6;
  const int wm = wv >> 1, wn = wv & 1;

  const float* Ag = x + (size_t)bm * 128 * D_;
  const float* Bg = Wi + (size_t)bn * 128 * D_;

  f32x4 acc[4][4];
#pragma unroll
  for (int mi = 0; mi < 4; ++mi)
#pragma unroll
    for (int nj = 0; nj < 4; ++nj) acc[mi][nj] = (f32x4){0.f, 0.f, 0.f, 0.f};

  const int r = tid >> 1;
  const int h2 = tid & 1;
  const int sw = r & 3;
  const int s0 = (h2 * 2) ^ sw, s1 = (h2 * 2 + 1) ^ sw;
  const int fr = lane & 15, kg = lane >> 4;

  for (int k0 = 0; k0 < D_; k0 += 32) {
    __syncthreads();
    {
      const float* pa = &Ag[(size_t)r * D_ + k0 + h2 * 16];
      const float* pb = &Bg[(size_t)r * D_ + k0 + h2 * 16];
      const float4 a0 = *(const float4*)(pa + 0), a1 = *(const float4*)(pa + 4);
      const float4 a2 = *(const float4*)(pa + 8), a3 = *(const float4*)(pa + 12);
      const float4 b0 = *(const float4*)(pb + 0), b1 = *(const float4*)(pb + 4);
      const float4 b2 = *(const float4*)(pb + 8), b3 = *(const float4*)(pb + 12);
      bf16x8 h, l;
      pack8(a0, a1, h, l);
      *(bf16x8*)&Ahi[r * 32 + s0 * 8] = h;
      *(bf16x8*)&Alo[r * 32 + s0 * 8] = l;
      pack8(a2, a3, h, l);
      *(bf16x8*)&Ahi[r * 32 + s1 * 8] = h;
      *(bf16x8*)&Alo[r * 32 + s1 * 8] = l;
      pack8(b0, b1, h, l);
      *(bf16x8*)&Bhi[r * 32 + s0 * 8] = h;
      *(bf16x8*)&Blo[r * 32 + s0 * 8] = l;
      pack8(b2, b3, h, l);
      *(bf16x8*)&Bhi[r * 32 + s1 * 8] = h;
      *(bf16x8*)&Blo[r * 32 + s1 * 8] = l;
    }
    __syncthreads();

    bf16x8 Ah[4], Al[4], Bh[4], Bl[4];
#pragma unroll
    for (int mi = 0; mi < 4; ++mi) {
      const int row = wm * 64 + mi * 16 + fr;
      const int sl = kg ^ (row & 3);
      Ah[mi] = *(const bf16x8*)&Ahi[row * 32 + sl * 8];
      Al[mi] = *(const bf16x8*)&Alo[row * 32 + sl * 8];
    }
#pragma unroll
    for (int nj = 0; nj < 4; ++nj) {
      const int row = wn * 64 + nj * 16 + fr;
      const int sl = kg ^ (row & 3);
      Bh[nj] = *(const bf16x8*)&Bhi[row * 32 + sl * 8];
      Bl[nj] = *(const bf16x8*)&Blo[row * 32 + sl * 8];
    }
#pragma unroll
    for (int mi = 0; mi < 4; ++mi)
#pragma unroll
      for (int nj = 0; nj < 4; ++nj) {
        acc[mi][nj] = __builtin_amdgcn_mfma_f32_16x16x32_bf16(
            Ah[mi], Bh[nj], acc[mi][nj], 0, 0, 0);
        acc[mi][nj] = __builtin_amdgcn_mfma_f32_16x16x32_bf16(
            Ah[mi], Bl[nj], acc[mi][nj], 0, 0, 0);
        acc[mi][nj] = __builtin_amdgcn_mfma_f32_16x16x32_bf16(
            Al[mi], Bh[nj], acc[mi][nj], 0, 0, 0);
      }
  }

  const int fq = lane >> 4;
#pragma unroll
  for (int nj = 0; nj < 4; ++nj) {
    const int col = bn * 128 + wn * 64 + nj * 16 + fr;
    const float bias = bi[col];
#pragma unroll
    for (int mi = 0; mi < 4; ++mi)
#pragma unroll
      for (int reg = 0; reg < 4; ++reg) {
        const size_t row = (size_t)bm * 128 + wm * 64 + mi * 16 + fq * 4 + reg;
        out[row * H_ + col] = acc[mi][nj][reg] + bias;
      }
  }
}

// ---------------------------------------------------------------------------
// Kernel B v8: h_t = tanh(xi_t + h_{t-1} @ Wh^T + bh)
//
// R2 sync skeleton (proven): vmcnt(0) -> __syncthreads -> tid0 flag store ->
// wave-0 poll -> __syncthreads. SINGLE structural change:
//
//  * ALL mutable global reads in the loop (h rows, xi) are agent-scope
//    relaxed ATOMIC loads (L1/L2-bypass -> always read the coherence point,
//    compiler-tracked). Staleness is impossible by construction, so the
//    per-step agent ACQUIRE FENCE IS DELETED — no more 512x512 full-L2
//    buffer_inv storms (the prime suspect for the 27 us/step stall: each
//    invalidate wipes the XCD's L2 and forces every subsequent load to
//    re-miss to MALL/HBM).
//  * h loads as 64-bit atomics (global_load_dwordx2): 2 per former float4.
//    Same skeleton, low VGPR (launch-safety lesson from R3-R6).
// ---------------------------------------------------------------------------
__global__ __launch_bounds__(256, 2) void rnn_scan(
    const float* __restrict__ h0, const float* __restrict__ Wh,
    const float* __restrict__ bh, float* __restrict__ out,
    unsigned int* __restrict__ flags) {
  __shared__ float Whs[16 * 1028];  // row r at r*1028 floats (2-way bank alias)
  const int tid = threadIdx.x;
  const int g = blockIdx.x & 7;
  const int c = blockIdx.x >> 3;
  const int j0 = c << 4;

#pragma unroll
  for (int it = 0; it < 16; ++it) {
    const int idx = (it << 8) + tid;
    const int r = idx >> 8;
    const int s4 = idx & 255;
    *(float4*)&Whs[r * 1028 + (s4 << 2)] =
        *(const float4*)&Wh[(size_t)(j0 + r) * H_ + (s4 << 2)];
  }

  const int lane = tid & 63;
  const int wv = tid >> 6;
  const int jl = lane & 15;                // 16 j per wave
  const int bl = (wv << 2) + (lane >> 4);  // 4 b per wave, 16 per block
  const int j = j0 + jl;
  const int b = (g << 4) + bl;
  const float bias = bh[j];
  const float* wrow = &Whs[jl * 1028];
  unsigned int* gflags = flags + (g << 6);
  __syncthreads();

  const unsigned long long* h64 =
      (const unsigned long long*)(h0 + (size_t)b * H_);
  for (int t = 0; t < L_; ++t) {
    const size_t oidx = ((size_t)t * B_ + b) * H_ + j;
    // xi: coherence-point read (bypasses caches; no stale line possible)
    const float xi_v = __hip_atomic_load(&out[oidx], __ATOMIC_RELAXED,
                                         __HIP_MEMORY_SCOPE_AGENT);
    float a0 = 0.f, a1 = 0.f, a2 = 0.f, a3 = 0.f;
#pragma unroll 8
    for (int s = 0; s < 256; ++s) {
      const float4 w = *(const float4*)&wrow[s << 2];  // ds_read_b128 imm
      const unsigned long long p = __hip_atomic_load(
          &h64[2 * s], __ATOMIC_RELAXED, __HIP_MEMORY_SCOPE_AGENT);
      const unsigned long long q = __hip_atomic_load(
          &h64[2 * s + 1], __ATOMIC_RELAXED, __HIP_MEMORY_SCOPE_AGENT);
      a0 += w.x * __uint_as_float((unsigned)p);
      a1 += w.y * __uint_as_float((unsigned)(p >> 32));
      a2 += w.z * __uint_as_float((unsigned)q);
      a3 += w.w * __uint_as_float((unsigned)(q >> 32));
    }
    const float v = tanhf((a0 + a1) + (a2 + a3) + xi_v + bias);
    // Write-through to coherence point (same as R2/R7).
    __hip_atomic_store(&out[oidx], v, __ATOMIC_RELAXED, __HIP_MEMORY_SCOPE_AGENT);

    if (t + 1 < L_) {
      // ---- release: drain my stores, block-wide done, publish (R2 path) ----
      asm volatile("s_waitcnt vmcnt(0)" ::: "memory");
      __syncthreads();
      if (tid == 0)
        __hip_atomic_store(&gflags[c], (unsigned)(t + 1), __ATOMIC_RELAXED,
                           __HIP_MEMORY_SCOPE_AGENT);
      // ---- wave 0 polls all 64 flags of the group ----
      if (tid < 64) {
        const unsigned tgt = (unsigned)(t + 1);
        while (true) {
          const unsigned f = __hip_atomic_load(&gflags[tid], __ATOMIC_RELAXED,
                                               __HIP_MEMORY_SCOPE_AGENT);
          if (__all((int)(f >= tgt))) break;
          __builtin_amdgcn_s_sleep(1);
        }
      }
      __syncthreads();
      // NO acquire fence: all mutable reads bypass L1/L2 by construction.
    }
    h64 = (const unsigned long long*)(out + ((size_t)t * B_ + b) * H_);
  }
}

// ---------------------------------------------------------------------------
extern "C" void kernel_launch(void* const* d_in, const int* in_sizes, int n_in,
                              void* d_out, int out_size, void* d_ws, size_t ws_size,
                              hipStream_t stream) {
  const float* x    = (const float*)d_in[0];
  const float* h0   = (const float*)d_in[1];
  const float* Wi_w = (const float*)d_in[2];
  const float* Wi_b = (const float*)d_in[3];
  const float* Wh_w = (const float*)d_in[4];
  const float* Wh_b = (const float*)d_in[5];
  float* out = (float*)d_out;
  unsigned int* flags = (unsigned int*)d_ws;

  // Phase 1: xi -> d_out (split-bf16 MFMA)
  hipLaunchKernelGGL(xi_gemm_mfma, dim3(512, 8), dim3(256), 0, stream,
                     x, Wi_w, Wi_b, out);

  // Zero the barrier flags (graph replays reuse d_ws; flags must start 0)
  hipMemsetAsync(d_ws, 0, 4096, stream);

  // Phase 2: cooperative scan
  void* args[] = { (void*)&h0, (void*)&Wh_w, (void*)&Wh_b, (void*)&out, (void*)&flags };
  hipLaunchCooperativeKernel((void*)rnn_scan, dim3(512), dim3(256), args, 0, stream);
}

// Round 9
// 13027.252 us; speedup vs baseline: 1.4887x; 1.4887x over previous
//
#include <hip/hip_runtime.h>
#include <cmath>

#define L_ 512
#define B_ 128
#define D_ 1024
#define H_ 1024

typedef __attribute__((ext_vector_type(8))) short bf16x8;
typedef __attribute__((ext_vector_type(4))) float f32x4;

static __device__ __forceinline__ unsigned short f32_bf16_rn(float f) {
  unsigned u = __float_as_uint(f);
  u += 0x7FFFu + ((u >> 16) & 1u);
  return (unsigned short)(u >> 16);
}
static __device__ __forceinline__ float bf16_f32(unsigned short h) {
  return __uint_as_float(((unsigned)h) << 16);
}

static __device__ __forceinline__ void pack8(const float4& u, const float4& v,
                                             bf16x8& hi, bf16x8& lo) {
  float f[8] = {u.x, u.y, u.z, u.w, v.x, v.y, v.z, v.w};
#pragma unroll
  for (int i = 0; i < 8; ++i) {
    const unsigned short h = f32_bf16_rn(f[i]);
    hi[i] = (short)h;
    lo[i] = (short)f32_bf16_rn(f[i] - bf16_f32(h));
  }
}

// ---------------------------------------------------------------------------
// Kernel A: xi = x @ Wi^T + bi, split-bf16 3-MFMA. (unchanged — R7-proven)
// ---------------------------------------------------------------------------
__global__ __launch_bounds__(256) void xi_gemm_mfma(
    const float* __restrict__ x, const float* __restrict__ Wi,
    const float* __restrict__ bi, float* __restrict__ out) {
  __shared__ unsigned short Ahi[128 * 32], Alo[128 * 32];
  __shared__ unsigned short Bhi[128 * 32], Blo[128 * 32];
  const int tid = threadIdx.x;
  const int bm = blockIdx.x, bn = blockIdx.y;
  const int lane = tid & 63, wv = tid >> 6;
  const int wm = wv >> 1, wn = wv & 1;

  const float* Ag = x + (size_t)bm * 128 * D_;
  const float* Bg = Wi + (size_t)bn * 128 * D_;

  f32x4 acc[4][4];
#pragma unroll
  for (int mi = 0; mi < 4; ++mi)
#pragma unroll
    for (int nj = 0; nj < 4; ++nj) acc[mi][nj] = (f32x4){0.f, 0.f, 0.f, 0.f};

  const int r = tid >> 1;
  const int h2 = tid & 1;
  const int sw = r & 3;
  const int s0 = (h2 * 2) ^ sw, s1 = (h2 * 2 + 1) ^ sw;
  const int fr = lane & 15, kg = lane >> 4;

  for (int k0 = 0; k0 < D_; k0 += 32) {
    __syncthreads();
    {
      const float* pa = &Ag[(size_t)r * D_ + k0 + h2 * 16];
      const float* pb = &Bg[(size_t)r * D_ + k0 + h2 * 16];
      const float4 a0 = *(const float4*)(pa + 0), a1 = *(const float4*)(pa + 4);
      const float4 a2 = *(const float4*)(pa + 8), a3 = *(const float4*)(pa + 12);
      const float4 b0 = *(const float4*)(pb + 0), b1 = *(const float4*)(pb + 4);
      const float4 b2 = *(const float4*)(pb + 8), b3 = *(const float4*)(pb + 12);
      bf16x8 h, l;
      pack8(a0, a1, h, l);
      *(bf16x8*)&Ahi[r * 32 + s0 * 8] = h;
      *(bf16x8*)&Alo[r * 32 + s0 * 8] = l;
      pack8(a2, a3, h, l);
      *(bf16x8*)&Ahi[r * 32 + s1 * 8] = h;
      *(bf16x8*)&Alo[r * 32 + s1 * 8] = l;
      pack8(b0, b1, h, l);
      *(bf16x8*)&Bhi[r * 32 + s0 * 8] = h;
      *(bf16x8*)&Blo[r * 32 + s0 * 8] = l;
      pack8(b2, b3, h, l);
      *(bf16x8*)&Bhi[r * 32 + s1 * 8] = h;
      *(bf16x8*)&Blo[r * 32 + s1 * 8] = l;
    }
    __syncthreads();

    bf16x8 Ah[4], Al[4], Bh[4], Bl[4];
#pragma unroll
    for (int mi = 0; mi < 4; ++mi) {
      const int row = wm * 64 + mi * 16 + fr;
      const int sl = kg ^ (row & 3);
      Ah[mi] = *(const bf16x8*)&Ahi[row * 32 + sl * 8];
      Al[mi] = *(const bf16x8*)&Alo[row * 32 + sl * 8];
    }
#pragma unroll
    for (int nj = 0; nj < 4; ++nj) {
      const int row = wn * 64 + nj * 16 + fr;
      const int sl = kg ^ (row & 3);
      Bh[nj] = *(const bf16x8*)&Bhi[row * 32 + sl * 8];
      Bl[nj] = *(const bf16x8*)&Blo[row * 32 + sl * 8];
    }
#pragma unroll
    for (int mi = 0; mi < 4; ++mi)
#pragma unroll
      for (int nj = 0; nj < 4; ++nj) {
        acc[mi][nj] = __builtin_amdgcn_mfma_f32_16x16x32_bf16(
            Ah[mi], Bh[nj], acc[mi][nj], 0, 0, 0);
        acc[mi][nj] = __builtin_amdgcn_mfma_f32_16x16x32_bf16(
            Ah[mi], Bl[nj], acc[mi][nj], 0, 0, 0);
        acc[mi][nj] = __builtin_amdgcn_mfma_f32_16x16x32_bf16(
            Al[mi], Bh[nj], acc[mi][nj], 0, 0, 0);
      }
  }

  const int fq = lane >> 4;
#pragma unroll
  for (int nj = 0; nj < 4; ++nj) {
    const int col = bn * 128 + wn * 64 + nj * 16 + fr;
    const float bias = bi[col];
#pragma unroll
    for (int mi = 0; mi < 4; ++mi)
#pragma unroll
      for (int reg = 0; reg < 4; ++reg) {
        const size_t row = (size_t)bm * 128 + wm * 64 + mi * 16 + fq * 4 + reg;
        out[row * H_ + col] = acc[mi][nj][reg] + bias;
      }
  }
}

// ---------------------------------------------------------------------------
// Kernel B v9: h_t = tanh(xi_t + h_{t-1} @ Wh^T + bh) — MFMA compute core.
//
// Sync skeleton, exchange format (f32 in-place in out[]), fences: VERBATIM
// R2/R7 (proven). v8 post-mortem: fence removal + bypass loads was SLOWER
// (19.4 vs 17.3 ms) -> stall is per-step pipe work (2048 ds_read_b128 +
// 2048 VMEM + VALU dot product per CU per step), not sync latency.
//
// New compute core: per block-step the output is one 16j x 16b MFMA tile,
// K=1024 split 4-ways across waves (256 k each = 8 tiles of 16x16x32).
//  * Wh is STATIC: pre-split to bf16 hi/lo in LDS ONCE (64 KB), stored in
//    fragment layout (lane fr reads row fr, k-slot kslot), slot XOR-swizzled
//    by (fr&7) -> <=2-way bank alias on ds_read_b128 (free).
//  * Per wave-step: 16 ds_read_b128 + 16 float4 h-loads + 24 MFMA
//    (vs 256 DS + 256 VMEM + ~1300 VALU). Split-bf16 hi*hi+hi*lo+lo*hi.
//  * Cross-wave K-reduce via LDS (stride-17 pad -> conflict-free reads),
//    one extra block-local __syncthreads. Finishing thread (j=tid&15,
//    b=tid>>4): sum + xi + bias, tanh, agent write-through store (R2 path).
// ---------------------------------------------------------------------------
__global__ __launch_bounds__(256, 2) void rnn_scan(
    const float* __restrict__ h0, const float* __restrict__ Wh,
    const float* __restrict__ bh, float* __restrict__ out,
    unsigned int* __restrict__ flags) {
  __shared__ unsigned short WhHi[16 * 1024];  // 32 KB
  __shared__ unsigned short WhLo[16 * 1024];  // 32 KB
  __shared__ float red[4 * 16 * 17];          // 4.25 KB, stride-17 pad
  const int tid = threadIdx.x;
  const int g = blockIdx.x & 7;
  const int c = blockIdx.x >> 3;
  const int j0 = c << 4;
  const int b0 = g << 4;

  // ---- Stage Wh rows j0..j0+15 as split-bf16, fragment-swizzled (once) ----
#pragma unroll
  for (int i = 0; i < 8; ++i) {
    const int sid = i * 256 + tid;      // 2048 slots of 8 elements
    const int jr = sid >> 7;            // 0..15
    const int s = sid & 127;            // k-slot
    const float* p = &Wh[(size_t)(j0 + jr) * H_ + s * 8];
    const float4 u = *(const float4*)(p);
    const float4 v4 = *(const float4*)(p + 4);
    bf16x8 hi, lo;
    pack8(u, v4, hi, lo);
    const int ps = s ^ (jr & 7);
    *(bf16x8*)&WhHi[jr * 1024 + ps * 8] = hi;
    *(bf16x8*)&WhLo[jr * 1024 + ps * 8] = lo;
  }

  const int lane = tid & 63;
  const int wv = tid >> 6;
  const int fr = lane & 15;        // A-row (j) / B-row (b) fragment index
  const int kb = lane >> 4;        // k-block within 32-k tile
  const int frx7 = fr & 7;
  const int frt = fr * 1024;
  const int wvk = wv * 256;        // this wave's K range
  const int jq = lane >> 4;        // D row-quad
  const int db = lane & 15;        // D col (b)
  // finishing-thread mapping (coalesced: lanes 0-15 consecutive j)
  const int jf = tid & 15;
  const int bf = tid >> 4;
  const float bias = bh[j0 + jf];
  unsigned int* gflags = flags + (g << 6);
  __syncthreads();

  const float* hbase = h0 + (size_t)b0 * H_;  // batch-b0 row base of h_{t-1}
  const size_t hoff = (size_t)fr * H_ + kb * 8;
  for (int t = 0; t < L_; ++t) {
    f32x4 acc = (f32x4){0.f, 0.f, 0.f, 0.f};
#pragma unroll
    for (int kt = 0; kt < 8; ++kt) {
      const int k0 = wvk + kt * 32;
      // B-frag: h[b = b0+fr][k0 + kb*8 ..+7], plain loads (post-fence, R2)
      const float4 u = *(const float4*)&hbase[hoff + k0];
      const float4 v4 = *(const float4*)&hbase[hoff + k0 + 4];
      bf16x8 Bh, Bl;
      pack8(u, v4, Bh, Bl);
      // A-frag: Wh[j = j0+fr][same k], from swizzled LDS
      const int ps = ((k0 >> 3) + kb) ^ frx7;
      const bf16x8 Ah = *(const bf16x8*)&WhHi[frt + ps * 8];
      const bf16x8 Al = *(const bf16x8*)&WhLo[frt + ps * 8];
      acc = __builtin_amdgcn_mfma_f32_16x16x32_bf16(Ah, Bh, acc, 0, 0, 0);
      acc = __builtin_amdgcn_mfma_f32_16x16x32_bf16(Ah, Bl, acc, 0, 0, 0);
      acc = __builtin_amdgcn_mfma_f32_16x16x32_bf16(Al, Bh, acc, 0, 0, 0);
    }
    // xi preload (issues before the reduce barrier; hides HBM latency)
    const size_t oidx = ((size_t)t * B_ + (b0 + bf)) * H_ + (j0 + jf);
    const float xi_v = out[oidx];
    // K-partials -> LDS (D map: col=lane&15 -> b, row=(lane>>4)*4+reg -> j)
#pragma unroll
    for (int r4 = 0; r4 < 4; ++r4)
      red[(wv * 16 + jq * 4 + r4) * 17 + db] = acc[r4];
    __syncthreads();
    const float sum = red[(0 * 16 + jf) * 17 + bf] + red[(1 * 16 + jf) * 17 + bf] +
                      red[(2 * 16 + jf) * 17 + bf] + red[(3 * 16 + jf) * 17 + bf];
    const float v = tanhf(sum + xi_v + bias);
    // Write-through to coherence point (R2 path).
    __hip_atomic_store(&out[oidx], v, __ATOMIC_RELAXED, __HIP_MEMORY_SCOPE_AGENT);

    if (t + 1 < L_) {
      // ---- release: drain stores, block done, publish (R2, verbatim) ----
      asm volatile("s_waitcnt vmcnt(0)" ::: "memory");
      __syncthreads();
      if (tid == 0)
        __hip_atomic_store(&gflags[c], (unsigned)(t + 1), __ATOMIC_RELAXED,
                           __HIP_MEMORY_SCOPE_AGENT);
      // ---- wave 0 polls all 64 group flags ----
      if (tid < 64) {
        const unsigned tgt = (unsigned)(t + 1);
        while (true) {
          const unsigned f = __hip_atomic_load(&gflags[tid], __ATOMIC_RELAXED,
                                               __HIP_MEMORY_SCOPE_AGENT);
          if (__all((int)(f >= tgt))) break;
          __builtin_amdgcn_s_sleep(1);
        }
      }
      __syncthreads();
      // Invalidate stale L1/L2 lines (peers' h written through to MALL).
      __builtin_amdgcn_fence(__ATOMIC_ACQUIRE, "agent");
    }
    hbase = out + (size_t)t * B_ * H_ + (size_t)b0 * H_;
  }
}

// ---------------------------------------------------------------------------
extern "C" void kernel_launch(void* const* d_in, const int* in_sizes, int n_in,
                              void* d_out, int out_size, void* d_ws, size_t ws_size,
                              hipStream_t stream) {
  const float* x    = (const float*)d_in[0];
  const float* h0   = (const float*)d_in[1];
  const float* Wi_w = (const float*)d_in[2];
  const float* Wi_b = (const float*)d_in[3];
  const float* Wh_w = (const float*)d_in[4];
  const float* Wh_b = (const float*)d_in[5];
  float* out = (float*)d_out;
  unsigned int* flags = (unsigned int*)d_ws;

  // Phase 1: xi -> d_out (split-bf16 MFMA)
  hipLaunchKernelGGL(xi_gemm_mfma, dim3(512, 8), dim3(256), 0, stream,
                     x, Wi_w, Wi_b, out);

  // Zero the barrier flags (graph replays reuse d_ws; flags must start 0)
  hipMemsetAsync(d_ws, 0, 4096, stream);

  // Phase 2: cooperative scan (MFMA core, R2 sync skeleton)
  void* args[] = { (void*)&h0, (void*)&Wh_w, (void*)&Wh_b, (void*)&out, (void*)&flags };
  hipLaunchCooperativeKernel((void*)rnn_scan, dim3(512), dim3(256), args, 0, stream);
}

// Round 10
// 7001.586 us; speedup vs baseline: 2.7700x; 1.8606x over previous
//
#include <hip/hip_runtime.h>
#include <cmath>

#define L_ 512
#define B_ 128
#define D_ 1024
#define H_ 1024

typedef __attribute__((ext_vector_type(8))) short bf16x8;
typedef __attribute__((ext_vector_type(4))) float f32x4;

static __device__ __forceinline__ unsigned short f32_bf16_rn(float f) {
  unsigned u = __float_as_uint(f);
  u += 0x7FFFu + ((u >> 16) & 1u);
  return (unsigned short)(u >> 16);
}
static __device__ __forceinline__ float bf16_f32(unsigned short h) {
  return __uint_as_float(((unsigned)h) << 16);
}

static __device__ __forceinline__ void pack8(const float4& u, const float4& v,
                                             bf16x8& hi, bf16x8& lo) {
  float f[8] = {u.x, u.y, u.z, u.w, v.x, v.y, v.z, v.w};
#pragma unroll
  for (int i = 0; i < 8; ++i) {
    const unsigned short h = f32_bf16_rn(f[i]);
    hi[i] = (short)h;
    lo[i] = (short)f32_bf16_rn(f[i] - bf16_f32(h));
  }
}

// ---------------------------------------------------------------------------
// Kernel A: xi = x @ Wi^T + bi, split-bf16 3-MFMA. (unchanged — R7-proven)
// ---------------------------------------------------------------------------
__global__ __launch_bounds__(256) void xi_gemm_mfma(
    const float* __restrict__ x, const float* __restrict__ Wi,
    const float* __restrict__ bi, float* __restrict__ out) {
  __shared__ unsigned short Ahi[128 * 32], Alo[128 * 32];
  __shared__ unsigned short Bhi[128 * 32], Blo[128 * 32];
  const int tid = threadIdx.x;
  const int bm = blockIdx.x, bn = blockIdx.y;
  const int lane = tid & 63, wv = tid >> 6;
  const int wm = wv >> 1, wn = wv & 1;

  const float* Ag = x + (size_t)bm * 128 * D_;
  const float* Bg = Wi + (size_t)bn * 128 * D_;

  f32x4 acc[4][4];
#pragma unroll
  for (int mi = 0; mi < 4; ++mi)
#pragma unroll
    for (int nj = 0; nj < 4; ++nj) acc[mi][nj] = (f32x4){0.f, 0.f, 0.f, 0.f};

  const int r = tid >> 1;
  const int h2 = tid & 1;
  const int sw = r & 3;
  const int s0 = (h2 * 2) ^ sw, s1 = (h2 * 2 + 1) ^ sw;
  const int fr = lane & 15, kg = lane >> 4;

  for (int k0 = 0; k0 < D_; k0 += 32) {
    __syncthreads();
    {
      const float* pa = &Ag[(size_t)r * D_ + k0 + h2 * 16];
      const float* pb = &Bg[(size_t)r * D_ + k0 + h2 * 16];
      const float4 a0 = *(const float4*)(pa + 0), a1 = *(const float4*)(pa + 4);
      const float4 a2 = *(const float4*)(pa + 8), a3 = *(const float4*)(pa + 12);
      const float4 b0 = *(const float4*)(pb + 0), b1 = *(const float4*)(pb + 4);
      const float4 b2 = *(const float4*)(pb + 8), b3 = *(const float4*)(pb + 12);
      bf16x8 h, l;
      pack8(a0, a1, h, l);
      *(bf16x8*)&Ahi[r * 32 + s0 * 8] = h;
      *(bf16x8*)&Alo[r * 32 + s0 * 8] = l;
      pack8(a2, a3, h, l);
      *(bf16x8*)&Ahi[r * 32 + s1 * 8] = h;
      *(bf16x8*)&Alo[r * 32 + s1 * 8] = l;
      pack8(b0, b1, h, l);
      *(bf16x8*)&Bhi[r * 32 + s0 * 8] = h;
      *(bf16x8*)&Blo[r * 32 + s0 * 8] = l;
      pack8(b2, b3, h, l);
      *(bf16x8*)&Bhi[r * 32 + s1 * 8] = h;
      *(bf16x8*)&Blo[r * 32 + s1 * 8] = l;
    }
    __syncthreads();

    bf16x8 Ah[4], Al[4], Bh[4], Bl[4];
#pragma unroll
    for (int mi = 0; mi < 4; ++mi) {
      const int row = wm * 64 + mi * 16 + fr;
      const int sl = kg ^ (row & 3);
      Ah[mi] = *(const bf16x8*)&Ahi[row * 32 + sl * 8];
      Al[mi] = *(const bf16x8*)&Alo[row * 32 + sl * 8];
    }
#pragma unroll
    for (int nj = 0; nj < 4; ++nj) {
      const int row = wn * 64 + nj * 16 + fr;
      const int sl = kg ^ (row & 3);
      Bh[nj] = *(const bf16x8*)&Bhi[row * 32 + sl * 8];
      Bl[nj] = *(const bf16x8*)&Blo[row * 32 + sl * 8];
    }
#pragma unroll
    for (int mi = 0; mi < 4; ++mi)
#pragma unroll
      for (int nj = 0; nj < 4; ++nj) {
        acc[mi][nj] = __builtin_amdgcn_mfma_f32_16x16x32_bf16(
            Ah[mi], Bh[nj], acc[mi][nj], 0, 0, 0);
        acc[mi][nj] = __builtin_amdgcn_mfma_f32_16x16x32_bf16(
            Ah[mi], Bl[nj], acc[mi][nj], 0, 0, 0);
        acc[mi][nj] = __builtin_amdgcn_mfma_f32_16x16x32_bf16(
            Al[mi], Bh[nj], acc[mi][nj], 0, 0, 0);
      }
  }

  const int fq = lane >> 4;
#pragma unroll
  for (int nj = 0; nj < 4; ++nj) {
    const int col = bn * 128 + wn * 64 + nj * 16 + fr;
    const float bias = bi[col];
#pragma unroll
    for (int mi = 0; mi < 4; ++mi)
#pragma unroll
      for (int reg = 0; reg < 4; ++reg) {
        const size_t row = (size_t)bm * 128 + wm * 64 + mi * 16 + fq * 4 + reg;
        out[row * H_ + col] = acc[mi][nj][reg] + bias;
      }
  }
}

// ---------------------------------------------------------------------------
// Kernel B v10: h_t = tanh(xi_t + h_{t-1} @ Wh^T + bh) — MFMA core (R9).
//
// R2 sync skeleton preserved. Two sync-neutral changes vs v9 (whose stall
// is ~22 us/step with ALL pipes <7% busy):
//
//  1. ACQUIRE FENCE ONLY IN WAVE 0 (+ __syncthreads). buffer_inv is a
//     physical cache op: it invalidates the CU's L1 and the XCD's L2 for
//     everyone; 4 redundant per-wave invalidates per block per step = 256
//     L2-invalidates per XCD per step — a hidden serial resource (the
//     suspected dominant stall; v8 showed removing inv but losing L2
//     caching is a wash, so keep caching and cut the inv count 8x chip-wide).
//  2. xi REGISTER CARRY: xi[t+1] is immutable until OUR OWN step-t+1 write,
//     so fetch it during step t's compute (deep overlap, plain cached load)
//     and carry the VALUE in a register across the fence (registers aren't
//     invalidated). Removes the ~1 us post-inv xi HBM miss from the serial
//     sum->tanh->store->publish chain.
// ---------------------------------------------------------------------------
__global__ __launch_bounds__(256, 2) void rnn_scan(
    const float* __restrict__ h0, const float* __restrict__ Wh,
    const float* __restrict__ bh, float* __restrict__ out,
    unsigned int* __restrict__ flags) {
  __shared__ unsigned short WhHi[16 * 1024];  // 32 KB
  __shared__ unsigned short WhLo[16 * 1024];  // 32 KB
  __shared__ float red[4 * 16 * 17];          // 4.25 KB, stride-17 pad
  const int tid = threadIdx.x;
  const int g = blockIdx.x & 7;
  const int c = blockIdx.x >> 3;
  const int j0 = c << 4;
  const int b0 = g << 4;

  // ---- Stage Wh rows j0..j0+15 as split-bf16, fragment-swizzled (once) ----
#pragma unroll
  for (int i = 0; i < 8; ++i) {
    const int sid = i * 256 + tid;
    const int jr = sid >> 7;
    const int s = sid & 127;
    const float* p = &Wh[(size_t)(j0 + jr) * H_ + s * 8];
    const float4 u = *(const float4*)(p);
    const float4 v4 = *(const float4*)(p + 4);
    bf16x8 hi, lo;
    pack8(u, v4, hi, lo);
    const int ps = s ^ (jr & 7);
    *(bf16x8*)&WhHi[jr * 1024 + ps * 8] = hi;
    *(bf16x8*)&WhLo[jr * 1024 + ps * 8] = lo;
  }

  const int lane = tid & 63;
  const int wv = tid >> 6;
  const int fr = lane & 15;
  const int kb = lane >> 4;
  const int frx7 = fr & 7;
  const int frt = fr * 1024;
  const int wvk = wv * 256;
  const int jq = lane >> 4;
  const int db = lane & 15;
  const int jf = tid & 15;
  const int bf = tid >> 4;
  const float bias = bh[j0 + jf];
  unsigned int* gflags = flags + (g << 6);
  __syncthreads();

  const float* hbase = h0 + (size_t)b0 * H_;
  const size_t hoff = (size_t)fr * H_ + kb * 8;
  const size_t obase = (size_t)(b0 + bf) * H_ + (j0 + jf);  // oidx = t*B*H + obase
  float xi_cur = out[obase];  // xi[t=0] (immutable until our t=0 store)
  for (int t = 0; t < L_; ++t) {
    f32x4 acc = (f32x4){0.f, 0.f, 0.f, 0.f};
#pragma unroll
    for (int kt = 0; kt < 8; ++kt) {
      const int k0 = wvk + kt * 32;
      const float4 u = *(const float4*)&hbase[hoff + k0];
      const float4 v4 = *(const float4*)&hbase[hoff + k0 + 4];
      bf16x8 Bh, Bl;
      pack8(u, v4, Bh, Bl);
      const int ps = ((k0 >> 3) + kb) ^ frx7;
      const bf16x8 Ah = *(const bf16x8*)&WhHi[frt + ps * 8];
      const bf16x8 Al = *(const bf16x8*)&WhLo[frt + ps * 8];
      acc = __builtin_amdgcn_mfma_f32_16x16x32_bf16(Ah, Bh, acc, 0, 0, 0);
      acc = __builtin_amdgcn_mfma_f32_16x16x32_bf16(Ah, Bl, acc, 0, 0, 0);
      acc = __builtin_amdgcn_mfma_f32_16x16x32_bf16(Al, Bh, acc, 0, 0, 0);
    }
    const size_t oidx = (size_t)t * B_ * H_ + obase;
    // Prefetch xi[t+1] NOW (overlaps reduce+release+poll; value is immutable
    // until our own t+1 store; register survives the fence). Last step reads
    // its own cell back — discarded.
    const size_t oidx_n = oidx + (size_t)(t + 1 < L_ ? B_ * H_ : 0);
    const float xi_next = out[oidx_n];
    // K-partials -> LDS (D map: col=lane&15 -> b, row=(lane>>4)*4+reg -> j)
#pragma unroll
    for (int r4 = 0; r4 < 4; ++r4)
      red[(wv * 16 + jq * 4 + r4) * 17 + db] = acc[r4];
    __syncthreads();
    const float sum = red[(0 * 16 + jf) * 17 + bf] + red[(1 * 16 + jf) * 17 + bf] +
                      red[(2 * 16 + jf) * 17 + bf] + red[(3 * 16 + jf) * 17 + bf];
    const float v = tanhf(sum + xi_cur + bias);
    __hip_atomic_store(&out[oidx], v, __ATOMIC_RELAXED, __HIP_MEMORY_SCOPE_AGENT);

    if (t + 1 < L_) {
      // ---- release: drain stores, block done, publish (R2, verbatim) ----
      asm volatile("s_waitcnt vmcnt(0)" ::: "memory");
      __syncthreads();
      if (tid == 0)
        __hip_atomic_store(&gflags[c], (unsigned)(t + 1), __ATOMIC_RELAXED,
                           __HIP_MEMORY_SCOPE_AGENT);
      // ---- wave 0: poll all 64 group flags, then ONE acquire fence ----
      if (tid < 64) {
        const unsigned tgt = (unsigned)(t + 1);
        while (true) {
          const unsigned f = __hip_atomic_load(&gflags[tid], __ATOMIC_RELAXED,
                                               __HIP_MEMORY_SCOPE_AGENT);
          if (__all((int)(f >= tgt))) break;
          __builtin_amdgcn_s_sleep(1);
        }
        // One buffer_inv per block: physically invalidates the CU's L1 and
        // the XCD's L2 for all waves; __syncthreads orders the others.
        __builtin_amdgcn_fence(__ATOMIC_ACQUIRE, "agent");
      }
      __syncthreads();
    }
    xi_cur = xi_next;
    hbase = out + (size_t)t * B_ * H_ + (size_t)b0 * H_;
  }
}

// ---------------------------------------------------------------------------
extern "C" void kernel_launch(void* const* d_in, const int* in_sizes, int n_in,
                              void* d_out, int out_size, void* d_ws, size_t ws_size,
                              hipStream_t stream) {
  const float* x    = (const float*)d_in[0];
  const float* h0   = (const float*)d_in[1];
  const float* Wi_w = (const float*)d_in[2];
  const float* Wi_b = (const float*)d_in[3];
  const float* Wh_w = (const float*)d_in[4];
  const float* Wh_b = (const float*)d_in[5];
  float* out = (float*)d_out;
  unsigned int* flags = (unsigned int*)d_ws;

  // Phase 1: xi -> d_out (split-bf16 MFMA)
  hipLaunchKernelGGL(xi_gemm_mfma, dim3(512, 8), dim3(256), 0, stream,
                     x, Wi_w, Wi_b, out);

  // Zero the barrier flags (graph replays reuse d_ws; flags must start 0)
  hipMemsetAsync(d_ws, 0, 4096, stream);

  // Phase 2: cooperative scan (MFMA core, R2 sync skeleton)
  void* args[] = { (void*)&h0, (void*)&Wh_w, (void*)&Wh_b, (void*)&out, (void*)&flags };
  hipLaunchCooperativeKernel((void*)rnn_scan, dim3(512), dim3(256), args, 0, stream);
}

// Round 11
// 6478.387 us; speedup vs baseline: 2.9937x; 1.0808x over previous
//
#include <hip/hip_runtime.h>
#include <cmath>

#define L_ 512
#define B_ 128
#define D_ 1024
#define H_ 1024

typedef __attribute__((ext_vector_type(8))) short bf16x8;
typedef __attribute__((ext_vector_type(4))) float f32x4;

static __device__ __forceinline__ unsigned short f32_bf16_rn(float f) {
  unsigned u = __float_as_uint(f);
  u += 0x7FFFu + ((u >> 16) & 1u);
  return (unsigned short)(u >> 16);
}
static __device__ __forceinline__ float bf16_f32(unsigned short h) {
  return __uint_as_float(((unsigned)h) << 16);
}

static __device__ __forceinline__ void pack8(const float4& u, const float4& v,
                                             bf16x8& hi, bf16x8& lo) {
  float f[8] = {u.x, u.y, u.z, u.w, v.x, v.y, v.z, v.w};
#pragma unroll
  for (int i = 0; i < 8; ++i) {
    const unsigned short h = f32_bf16_rn(f[i]);
    hi[i] = (short)h;
    lo[i] = (short)f32_bf16_rn(f[i] - bf16_f32(h));
  }
}

// ---------------------------------------------------------------------------
// Kernel A: xi = x @ Wi^T + bi, split-bf16 3-MFMA. (unchanged — R7-proven)
// ---------------------------------------------------------------------------
__global__ __launch_bounds__(256) void xi_gemm_mfma(
    const float* __restrict__ x, const float* __restrict__ Wi,
    const float* __restrict__ bi, float* __restrict__ out) {
  __shared__ unsigned short Ahi[128 * 32], Alo[128 * 32];
  __shared__ unsigned short Bhi[128 * 32], Blo[128 * 32];
  const int tid = threadIdx.x;
  const int bm = blockIdx.x, bn = blockIdx.y;
  const int lane = tid & 63, wv = tid >> 6;
  const int wm = wv >> 1, wn = wv & 1;

  const float* Ag = x + (size_t)bm * 128 * D_;
  const float* Bg = Wi + (size_t)bn * 128 * D_;

  f32x4 acc[4][4];
#pragma unroll
  for (int mi = 0; mi < 4; ++mi)
#pragma unroll
    for (int nj = 0; nj < 4; ++nj) acc[mi][nj] = (f32x4){0.f, 0.f, 0.f, 0.f};

  const int r = tid >> 1;
  const int h2 = tid & 1;
  const int sw = r & 3;
  const int s0 = (h2 * 2) ^ sw, s1 = (h2 * 2 + 1) ^ sw;
  const int fr = lane & 15, kg = lane >> 4;

  for (int k0 = 0; k0 < D_; k0 += 32) {
    __syncthreads();
    {
      const float* pa = &Ag[(size_t)r * D_ + k0 + h2 * 16];
      const float* pb = &Bg[(size_t)r * D_ + k0 + h2 * 16];
      const float4 a0 = *(const float4*)(pa + 0), a1 = *(const float4*)(pa + 4);
      const float4 a2 = *(const float4*)(pa + 8), a3 = *(const float4*)(pa + 12);
      const float4 b0 = *(const float4*)(pb + 0), b1 = *(const float4*)(pb + 4);
      const float4 b2 = *(const float4*)(pb + 8), b3 = *(const float4*)(pb + 12);
      bf16x8 h, l;
      pack8(a0, a1, h, l);
      *(bf16x8*)&Ahi[r * 32 + s0 * 8] = h;
      *(bf16x8*)&Alo[r * 32 + s0 * 8] = l;
      pack8(a2, a3, h, l);
      *(bf16x8*)&Ahi[r * 32 + s1 * 8] = h;
      *(bf16x8*)&Alo[r * 32 + s1 * 8] = l;
      pack8(b0, b1, h, l);
      *(bf16x8*)&Bhi[r * 32 + s0 * 8] = h;
      *(bf16x8*)&Blo[r * 32 + s0 * 8] = l;
      pack8(b2, b3, h, l);
      *(bf16x8*)&Bhi[r * 32 + s1 * 8] = h;
      *(bf16x8*)&Blo[r * 32 + s1 * 8] = l;
    }
    __syncthreads();

    bf16x8 Ah[4], Al[4], Bh[4], Bl[4];
#pragma unroll
    for (int mi = 0; mi < 4; ++mi) {
      const int row = wm * 64 + mi * 16 + fr;
      const int sl = kg ^ (row & 3);
      Ah[mi] = *(const bf16x8*)&Ahi[row * 32 + sl * 8];
      Al[mi] = *(const bf16x8*)&Alo[row * 32 + sl * 8];
    }
#pragma unroll
    for (int nj = 0; nj < 4; ++nj) {
      const int row = wn * 64 + nj * 16 + fr;
      const int sl = kg ^ (row & 3);
      Bh[nj] = *(const bf16x8*)&Bhi[row * 32 + sl * 8];
      Bl[nj] = *(const bf16x8*)&Blo[row * 32 + sl * 8];
    }
#pragma unroll
    for (int mi = 0; mi < 4; ++mi)
#pragma unroll
      for (int nj = 0; nj < 4; ++nj) {
        acc[mi][nj] = __builtin_amdgcn_mfma_f32_16x16x32_bf16(
            Ah[mi], Bh[nj], acc[mi][nj], 0, 0, 0);
        acc[mi][nj] = __builtin_amdgcn_mfma_f32_16x16x32_bf16(
            Ah[mi], Bl[nj], acc[mi][nj], 0, 0, 0);
        acc[mi][nj] = __builtin_amdgcn_mfma_f32_16x16x32_bf16(
            Al[mi], Bh[nj], acc[mi][nj], 0, 0, 0);
      }
  }

  const int fq = lane >> 4;
#pragma unroll
  for (int nj = 0; nj < 4; ++nj) {
    const int col = bn * 128 + wn * 64 + nj * 16 + fr;
    const float bias = bi[col];
#pragma unroll
    for (int mi = 0; mi < 4; ++mi)
#pragma unroll
      for (int reg = 0; reg < 4; ++reg) {
        const size_t row = (size_t)bm * 128 + wm * 64 + mi * 16 + fq * 4 + reg;
        out[row * H_ + col] = acc[mi][nj][reg] + bias;
      }
  }
}

// ---------------------------------------------------------------------------
// Kernel B v11: h_t = tanh(xi_t + h_{t-1} @ Wh^T + bh) — MFMA core.
//
// R2 sync skeleton preserved EXCEPT the acquire fence is now deleted:
//  * h-loads are agent-scope bypass atomic loads (64-bit) — always read the
//    coherence point. Under the MFMA core this is only 32 VMEM/wave-step
//    (v8's failed bypass attempt was 512/wave-step — different regime), and
//    post-inv cached loads missed to MALL anyway, so caching h bought nothing.
//  * With h bypassed, NOTHING mutable-stale remains cached: xi-prefetch
//    lines (one 64B line per batch: j0..j0+15) are written ONLY by this
//    block; flags already bypass; Wh staged once from immutable input.
//    => zero buffer_inv in the loop: no L2 tag-pipe serialization (64
//    invalidates/XCD/step), no post-inv miss storms.
//  * Ordering: h bypass loads are emitted after the post-poll __syncthreads
//    (exec+memory barrier); producers' h write-throughs reached MALL before
//    their flag store (R2-lineage, empirically validated R2/R7/R9/R10).
// ---------------------------------------------------------------------------
__global__ __launch_bounds__(256, 2) void rnn_scan(
    const float* __restrict__ h0, const float* __restrict__ Wh,
    const float* __restrict__ bh, float* __restrict__ out,
    unsigned int* __restrict__ flags) {
  __shared__ unsigned short WhHi[16 * 1024];  // 32 KB
  __shared__ unsigned short WhLo[16 * 1024];  // 32 KB
  __shared__ float red[4 * 16 * 17];          // 4.25 KB, stride-17 pad
  const int tid = threadIdx.x;
  const int g = blockIdx.x & 7;
  const int c = blockIdx.x >> 3;
  const int j0 = c << 4;
  const int b0 = g << 4;

  // ---- Stage Wh rows j0..j0+15 as split-bf16, fragment-swizzled (once) ----
#pragma unroll
  for (int i = 0; i < 8; ++i) {
    const int sid = i * 256 + tid;
    const int jr = sid >> 7;
    const int s = sid & 127;
    const float* p = &Wh[(size_t)(j0 + jr) * H_ + s * 8];
    const float4 u = *(const float4*)(p);
    const float4 v4 = *(const float4*)(p + 4);
    bf16x8 hi, lo;
    pack8(u, v4, hi, lo);
    const int ps = s ^ (jr & 7);
    *(bf16x8*)&WhHi[jr * 1024 + ps * 8] = hi;
    *(bf16x8*)&WhLo[jr * 1024 + ps * 8] = lo;
  }

  const int lane = tid & 63;
  const int wv = tid >> 6;
  const int fr = lane & 15;
  const int kb = lane >> 4;
  const int frx7 = fr & 7;
  const int frt = fr * 1024;
  const int wvk = wv * 256;
  const int jq = lane >> 4;
  const int db = lane & 15;
  const int jf = tid & 15;
  const int bf = tid >> 4;
  const float bias = bh[j0 + jf];
  unsigned int* gflags = flags + (g << 6);
  __syncthreads();

  // h base in 64-bit units; per-lane offset fr*512 + kb*4
  const unsigned long long* h64 =
      (const unsigned long long*)(h0 + (size_t)b0 * H_);
  const size_t hoff64 = (size_t)fr * (H_ / 2) + kb * 4;
  const size_t obase = (size_t)(b0 + bf) * H_ + (j0 + jf);
  float xi_cur = out[obase];  // xi[t=0] (line exclusively ours)
  for (int t = 0; t < L_; ++t) {
    f32x4 acc = (f32x4){0.f, 0.f, 0.f, 0.f};
#pragma unroll
    for (int kt = 0; kt < 8; ++kt) {
      const size_t k64 = hoff64 + (wvk >> 1) + kt * 16;
      // Bypass loads: always read the coherence point — no staleness, no inv.
      const unsigned long long p0 = __hip_atomic_load(
          &h64[k64 + 0], __ATOMIC_RELAXED, __HIP_MEMORY_SCOPE_AGENT);
      const unsigned long long p1 = __hip_atomic_load(
          &h64[k64 + 1], __ATOMIC_RELAXED, __HIP_MEMORY_SCOPE_AGENT);
      const unsigned long long p2 = __hip_atomic_load(
          &h64[k64 + 2], __ATOMIC_RELAXED, __HIP_MEMORY_SCOPE_AGENT);
      const unsigned long long p3 = __hip_atomic_load(
          &h64[k64 + 3], __ATOMIC_RELAXED, __HIP_MEMORY_SCOPE_AGENT);
      const float4 u = make_float4(__uint_as_float((unsigned)p0),
                                   __uint_as_float((unsigned)(p0 >> 32)),
                                   __uint_as_float((unsigned)p1),
                                   __uint_as_float((unsigned)(p1 >> 32)));
      const float4 v4 = make_float4(__uint_as_float((unsigned)p2),
                                    __uint_as_float((unsigned)(p2 >> 32)),
                                    __uint_as_float((unsigned)p3),
                                    __uint_as_float((unsigned)(p3 >> 32)));
      bf16x8 Bh, Bl;
      pack8(u, v4, Bh, Bl);
      const int ps = (((wvk + kt * 32) >> 3) + kb) ^ frx7;
      const bf16x8 Ah = *(const bf16x8*)&WhHi[frt + ps * 8];
      const bf16x8 Al = *(const bf16x8*)&WhLo[frt + ps * 8];
      acc = __builtin_amdgcn_mfma_f32_16x16x32_bf16(Ah, Bh, acc, 0, 0, 0);
      acc = __builtin_amdgcn_mfma_f32_16x16x32_bf16(Ah, Bl, acc, 0, 0, 0);
      acc = __builtin_amdgcn_mfma_f32_16x16x32_bf16(Al, Bh, acc, 0, 0, 0);
    }
    const size_t oidx = (size_t)t * B_ * H_ + obase;
    // xi[t+1] prefetch: plain cached load (line exclusively ours); register
    // carry across the step boundary (no fence to survive anymore).
    const size_t oidx_n = oidx + (size_t)(t + 1 < L_ ? B_ * H_ : 0);
    const float xi_next = out[oidx_n];
    // K-partials -> LDS (D map: col=lane&15 -> b, row=(lane>>4)*4+reg -> j)
#pragma unroll
    for (int r4 = 0; r4 < 4; ++r4)
      red[(wv * 16 + jq * 4 + r4) * 17 + db] = acc[r4];
    __syncthreads();
    const float sum = red[(0 * 16 + jf) * 17 + bf] + red[(1 * 16 + jf) * 17 + bf] +
                      red[(2 * 16 + jf) * 17 + bf] + red[(3 * 16 + jf) * 17 + bf];
    const float v = tanhf(sum + xi_cur + bias);
    __hip_atomic_store(&out[oidx], v, __ATOMIC_RELAXED, __HIP_MEMORY_SCOPE_AGENT);

    if (t + 1 < L_) {
      // ---- release: drain stores, block done, publish (R2, verbatim) ----
      asm volatile("s_waitcnt vmcnt(0)" ::: "memory");
      __syncthreads();
      if (tid == 0)
        __hip_atomic_store(&gflags[c], (unsigned)(t + 1), __ATOMIC_RELAXED,
                           __HIP_MEMORY_SCOPE_AGENT);
      // ---- wave 0: poll all 64 group flags; NO acquire fence needed ----
      if (tid < 64) {
        const unsigned tgt = (unsigned)(t + 1);
        while (true) {
          const unsigned f = __hip_atomic_load(&gflags[tid], __ATOMIC_RELAXED,
                                               __HIP_MEMORY_SCOPE_AGENT);
          if (__all((int)(f >= tgt))) break;
          __builtin_amdgcn_s_sleep(1);
        }
      }
      __syncthreads();  // exec+memory barrier: h loads below issue after poll
    }
    xi_cur = xi_next;
    h64 = (const unsigned long long*)(out + (size_t)t * B_ * H_ +
                                      (size_t)b0 * H_);
  }
}

// ---------------------------------------------------------------------------
extern "C" void kernel_launch(void* const* d_in, const int* in_sizes, int n_in,
                              void* d_out, int out_size, void* d_ws, size_t ws_size,
                              hipStream_t stream) {
  const float* x    = (const float*)d_in[0];
  const float* h0   = (const float*)d_in[1];
  const float* Wi_w = (const float*)d_in[2];
  const float* Wi_b = (const float*)d_in[3];
  const float* Wh_w = (const float*)d_in[4];
  const float* Wh_b = (const float*)d_in[5];
  float* out = (float*)d_out;
  unsigned int* flags = (unsigned int*)d_ws;

  // Phase 1: xi -> d_out (split-bf16 MFMA)
  hipLaunchKernelGGL(xi_gemm_mfma, dim3(512, 8), dim3(256), 0, stream,
                     x, Wi_w, Wi_b, out);

  // Zero the barrier flags (graph replays reuse d_ws; flags must start 0)
  hipMemsetAsync(d_ws, 0, 4096, stream);

  // Phase 2: cooperative scan (MFMA core, fence-free)
  void* args[] = { (void*)&h0, (void*)&Wh_w, (void*)&Wh_b, (void*)&out, (void*)&flags };
  hipLaunchCooperativeKernel((void*)rnn_scan, dim3(512), dim3(256), args, 0, stream);
}